// Round 15
// baseline (279.127 us; speedup 1.0000x reference)
//
#include <hip/hip_runtime.h>
#include <hip/hip_bf16.h>

typedef __attribute__((ext_vector_type(8))) short bf16x8;
typedef __attribute__((ext_vector_type(4))) short short4v;
typedef __attribute__((ext_vector_type(4))) float f32x4;

#define D        256
#define NH       512
#define NT       32               // n-tiles (16 cols each)
#define KT       8                // k-steps (32 each)
#define MT       4                // M-tiles per wave -> 64 rows/wave
#define ROWS_PER_BLOCK 128        // 2 waves per block
#define ROWS_TOTAL (32*8192)      // 262144

typedef __attribute__((address_space(1))) const void GV;
typedef __attribute__((address_space(3))) void LV;

__device__ __forceinline__ short f2bf(float f) {
    union { float f; unsigned u; } v; v.f = f;
    unsigned r = v.u + 0x7FFFu + ((v.u >> 16) & 1u);
    return (short)(r >> 16);
}
__device__ __forceinline__ float rcp_fast(float x) {
    return __builtin_amdgcn_rcpf(x);
}

// Pack We (fp32 [256][512]) into bf16 MFMA B-fragments:
// frag[(nt*8+kt)*64 + lane][j] = We[kt*32 + (lane>>4)*8 + j][nt*16 + (lane&15)]
// Also: bw[n] = (2*be[n], Wr[n]); Ssum = sum(Wr).
__global__ void prepack_B(const float* __restrict__ We, const float* __restrict__ be,
                          const float* __restrict__ Wr,
                          short* __restrict__ Bh, float2* __restrict__ bw,
                          float* __restrict__ Ssum) {
    int i = blockIdx.x * 256 + threadIdx.x;      // 131072 elements
    int k = i >> 9;
    int n = i & 511;
    int nt = n >> 4, c = n & 15;
    int kt = k >> 5, g = (k >> 3) & 3, j = k & 7;
    int idx = (((nt * 8 + kt) * 64) + (g * 16 + c)) * 8 + j;
    Bh[idx] = f2bf(We[i]);
    if (i < 512) bw[i] = make_float2(2.0f * be[i], Wr[i]);
    if (i == 0) {
        float s = 0.0f;
        for (int t = 0; t < 512; ++t) s += Wr[t];
        Ssum[0] = s;
    }
}

// 2-wave blocks sharing the B double-buffer (each wave stages its 4 kt);
// coalesced A-path via per-wave swizzled LDS transpose (scratch = Bl[wave]);
// full VM0 drains + 2-wave barrier per nt; bw table in LDS.
__global__ __launch_bounds__(128, 3) void softpool_main(
    const float* __restrict__ x, const short* __restrict__ Bh,
    const float2* __restrict__ bwg, const float* __restrict__ br,
    const float* __restrict__ Ssum, float* __restrict__ out)
{
    const int tid  = threadIdx.x;
    const int wave = tid >> 6;           // 0..1
    const int lane = tid & 63;
    const int c = lane & 15;             // A row-in-tile / C col / B col
    const int g = lane >> 4;             // k-group
    const long row0 = (long)blockIdx.x * ROWS_PER_BLOCK + (long)wave * 64;

    __shared__ short Bl[2][4096];        // B dbuf (16KB); Bl[w] = wave w A-scratch
    __shared__ float2 bwl[512];          // (2*be, Wr) table, 4KB

    // bw table -> LDS (once): 128 threads x 2 float4 = 4KB
    #pragma unroll
    for (int i = 0; i < 2; ++i)
        ((float4*)bwl)[tid * 2 + i] = ((const float4*)bwg)[tid * 2 + i];

    // Wave w stages kt = 4w..4w+3 (1KB each) of each nt-tile.
    const int kt0 = wave * 4;
    const short* gB = Bh + kt0 * 512 + lane * 8;

    #define STAGE(buf, ntv) {                                                  \
        const short* _g = gB + (long)(ntv) * 4096;                             \
        _Pragma("unroll")                                                      \
        for (int kk = 0; kk < 4; ++kk)                                         \
            __builtin_amdgcn_global_load_lds((GV*)(_g + kk * 512),             \
                (LV*)&Bl[buf][(kt0 + kk) * 512], 16, 0, 0);                    \
    }

    #define VM0 asm volatile("s_waitcnt vmcnt(0)" ::: "memory");

    // ---- A-phase: coalesced row loads -> bf16 -> swizzled transpose in
    //      this wave's private scratch Bl[wave] -> fragment regs.
    bf16x8 a[MT][KT];
    char* Asl = (char*)&Bl[wave][0];     // 8KB scratch (16 rows x 512B)
    #pragma unroll
    for (int m = 0; m < MT; ++m) {
        #pragma unroll
        for (int half = 0; half < 2; ++half) {
            const float* rb = x + (row0 + m * 16 + half * 8) * D;
            float4 st[8];
            #pragma unroll
            for (int i = 0; i < 8; ++i)
                st[i] = ((const float4*)(rb + i * D))[lane];   // coalesced 1KB/inst
            #pragma unroll
            for (int i = 0; i < 8; ++i) {
                const int row = half * 8 + i;                  // local row 0..15
                short4v t;
                t[0] = f2bf(st[i].x); t[1] = f2bf(st[i].y);
                t[2] = f2bf(st[i].z); t[3] = f2bf(st[i].w);
                const int boff = row * 512 + ((lane * 8) ^ ((row & 7) << 4));
                *(short4v*)(Asl + boff) = t;
            }
        }
        #pragma unroll
        for (int kt = 0; kt < KT; ++kt) {
            const int boff = c * 512 + ((kt * 64 + g * 16) ^ ((c & 7) << 4));
            a[m][kt] = *(const bf16x8*)(Asl + boff);
        }
    }

    float lps[MT][4];
    #pragma unroll
    for (int m = 0; m < MT; ++m)
        #pragma unroll
        for (int r = 0; r < 4; ++r) lps[m][r] = 0.0f;

    f32x4 acc[MT];

    #define MFMA_(buf) {                                                       \
        _Pragma("unroll")                                                      \
        for (int m = 0; m < MT; ++m)                                           \
            _Pragma("unroll")                                                  \
            for (int r = 0; r < 4; ++r) acc[m][r] = 0.0f;                      \
        _Pragma("unroll")                                                      \
        for (int kt = 0; kt < KT; ++kt) {                                      \
            bf16x8 b = *(const bf16x8*)&Bl[buf][kt * 512 + lane * 8];          \
            _Pragma("unroll")                                                  \
            for (int m = 0; m < MT; ++m)                                       \
                acc[m] = __builtin_amdgcn_mfma_f32_16x16x32_bf16(              \
                             a[m][kt], b, acc[m], 0, 0, 0);                    \
        }                                                                      \
    }

    #define TANH_(ntv) {                                                       \
        float2 bwv = bwl[(ntv) * 16 + c];                                      \
        _Pragma("unroll")                                                      \
        for (int m = 0; m < MT; ++m)                                           \
            _Pragma("unroll")                                                  \
            for (int r = 0; r < 4; ++r) {                                      \
                float z = __builtin_fmaf(acc[m][r], 2.0f, bwv.x);              \
                float e = __expf(z);                                           \
                float rr = rcp_fast(e + 1.0f);                                 \
                lps[m][r] = __builtin_fmaf(bwv.y, rr, lps[m][r]);              \
            }                                                                  \
    }

    __syncthreads();      // A-scratch reads done (both waves); bwl visible

    // ---- Main loop: shared B dbuf, 1 VM0 + 1 barrier per nt
    STAGE(0, 0)
    VM0; __syncthreads();          // tile 0 in Bl[0]
    STAGE(1, 1)
    MFMA_(0)                       // nt 0
    TANH_(0)
    VM0; __syncthreads();          // tile 1 ready; Bl[0] reads done (both waves)

    for (int it = 0; it < 15; ++it) {
        STAGE(0, 2 * it + 2)
        MFMA_(1)                   // nt = 2it+1
        TANH_(2 * it + 1)
        VM0; __syncthreads();
        STAGE(1, 2 * it + 3)
        MFMA_(0)                   // nt = 2it+2
        TANH_(2 * it + 2)
        VM0; __syncthreads();
    }
    MFMA_(1)                       // nt 31
    TANH_(31)

    // ---- Reduce partials over 16 cols; softmax(sigmoid); weighted output
    const float brv = br[0];
    const float S = Ssum[0];
    #pragma unroll
    for (int m = 0; m < MT; ++m) {
        float l0 = lps[m][0], l1 = lps[m][1], l2 = lps[m][2], l3 = lps[m][3];
        #pragma unroll
        for (int off = 1; off < 16; off <<= 1) {
            l0 += __shfl_xor(l0, off, 64);
            l1 += __shfl_xor(l1, off, 64);
            l2 += __shfl_xor(l2, off, 64);
            l3 += __shfl_xor(l3, off, 64);
        }
        float g0 = S - 2.0f * l0 + brv;
        float g1 = S - 2.0f * l1 + brv;
        float g2 = S - 2.0f * l2 + brv;
        float g3 = S - 2.0f * l3 + brv;
        float s0 = rcp_fast(1.0f + __expf(-g0));
        float s1 = rcp_fast(1.0f + __expf(-g1));
        float s2 = rcp_fast(1.0f + __expf(-g2));
        float s3 = rcp_fast(1.0f + __expf(-g3));
        float e0 = __expf(s0), e1 = __expf(s1), e2 = __expf(s2), e3 = __expf(s3);
        float inv = rcp_fast(e0 + e1 + e2 + e3);
        float w0 = e0 * inv, w1 = e1 * inv, w2 = e2 * inv, w3 = e3 * inv;

        // window = rows [wrow, wrow+3]; lane-group g owns window g of this Mtile
        // lane stores cols [c*4 + q*64 ..+3]: 16 lanes -> 256B contiguous runs
        const long wrow = row0 + m * 16 + g * 4;
        const long W = wrow >> 2;
        const float* xw = x + wrow * D + c * 4;
        float* op = out + W * D + c * 4;
        #pragma unroll
        for (int q = 0; q < 4; ++q) {
            float4 r0 = *(const float4*)(xw + 0 * D + q * 64);
            float4 r1 = *(const float4*)(xw + 1 * D + q * 64);
            float4 r2 = *(const float4*)(xw + 2 * D + q * 64);
            float4 r3 = *(const float4*)(xw + 3 * D + q * 64);
            float4 oo;
            oo.x = w0 * r0.x + w1 * r1.x + w2 * r2.x + w3 * r3.x;
            oo.y = w0 * r0.y + w1 * r1.y + w2 * r2.y + w3 * r3.y;
            oo.z = w0 * r0.z + w1 * r1.z + w2 * r2.z + w3 * r3.z;
            oo.w = w0 * r0.w + w1 * r1.w + w2 * r2.w + w3 * r3.w;
            *(float4*)(op + q * 64) = oo;
        }
    }
}

extern "C" void kernel_launch(void* const* d_in, const int* in_sizes, int n_in,
                              void* d_out, int out_size, void* d_ws, size_t ws_size,
                              hipStream_t stream) {
    const float* x  = (const float*)d_in[0];
    const float* We = (const float*)d_in[1];
    const float* be = (const float*)d_in[2];
    const float* Wr = (const float*)d_in[3];
    const float* br = (const float*)d_in[4];
    float* out = (float*)d_out;

    char* ws = (char*)d_ws;
    short*  Bh   = (short*)ws;                    // 262144 B
    float2* bwp  = (float2*)(ws + 262144);        // 4096 B
    float*  Ssum = (float*)(ws + 262144 + 4096);  // 4 B

    prepack_B<<<NH * D / 256, 256, 0, stream>>>(We, be, Wr, Bh, bwp, Ssum);

    const int blocks = ROWS_TOTAL / ROWS_PER_BLOCK;   // 2048
    softpool_main<<<blocks, 128, 0, stream>>>(x, Bh, bwp, br, Ssum, out);
}

// Round 17
// 156.696 us; speedup vs baseline: 1.7813x; 1.7813x over previous
//
#include <hip/hip_runtime.h>
#include <hip/hip_bf16.h>

typedef __attribute__((ext_vector_type(8))) short bf16x8;
typedef __attribute__((ext_vector_type(4))) short short4v;
typedef __attribute__((ext_vector_type(4))) float f32x4;

#define D        256
#define NH       512
#define NT       32               // n-tiles (16 cols each)
#define KT       8                // k-steps (32 each)
#define MT       4                // M-tiles per wave -> 64 rows/wave
#define ROWS_PER_BLOCK 128        // 2 waves per block
#define ROWS_TOTAL (32*8192)      // 262144

typedef __attribute__((address_space(1))) const void GV;
typedef __attribute__((address_space(3))) void LV;

__device__ __forceinline__ short f2bf(float f) {
    union { float f; unsigned u; } v; v.f = f;
    unsigned r = v.u + 0x7FFFu + ((v.u >> 16) & 1u);
    return (short)(r >> 16);
}
__device__ __forceinline__ float rcp_fast(float x) {
    return __builtin_amdgcn_rcpf(x);
}

// Pack We (fp32 [256][512]) into bf16 MFMA B-fragments:
// frag[(nt*8+kt)*64 + lane][j] = We[kt*32 + (lane>>4)*8 + j][nt*16 + (lane&15)]
// Also: bw[n] = (2*be[n], Wr[n]); Ssum = sum(Wr).
__global__ void prepack_B(const float* __restrict__ We, const float* __restrict__ be,
                          const float* __restrict__ Wr,
                          short* __restrict__ Bh, float2* __restrict__ bw,
                          float* __restrict__ Ssum) {
    int i = blockIdx.x * 256 + threadIdx.x;      // 131072 elements
    int k = i >> 9;
    int n = i & 511;
    int nt = n >> 4, c = n & 15;
    int kt = k >> 5, g = (k >> 3) & 3, j = k & 7;
    int idx = (((nt * 8 + kt) * 64) + (g * 16 + c)) * 8 + j;
    Bh[idx] = f2bf(We[i]);
    if (i < 512) bw[i] = make_float2(2.0f * be[i], Wr[i]);
    if (i == 0) {
        float s = 0.0f;
        for (int t = 0; t < 512; ++t) s += Wr[t];
        Ssum[0] = s;
    }
}

// 2-wave blocks sharing the B double-buffer (each wave stages its 4 kt);
// launch_bounds(128,2) so the 128-VGPR A-array does NOT spill (R15 lesson);
// stage-other-buffer-only + VM0 + barrier per nt (race-safe discipline);
// coalesced A-path via per-wave swizzled LDS transpose; deferred dbl-acc TANH.
__global__ __launch_bounds__(128, 2) void softpool_main(
    const float* __restrict__ x, const short* __restrict__ Bh,
    const float2* __restrict__ bwg, const float* __restrict__ br,
    const float* __restrict__ Ssum, float* __restrict__ out)
{
    const int tid  = threadIdx.x;
    const int wave = tid >> 6;           // 0..1
    const int lane = tid & 63;
    const int c = lane & 15;             // A row-in-tile / C col / B col
    const int g = lane >> 4;             // k-group
    const long row0 = (long)blockIdx.x * ROWS_PER_BLOCK + (long)wave * 64;

    __shared__ short Bl[2][4096];        // B dbuf (16KB); Bl[w] = wave w A-scratch
    __shared__ float2 bwl[512];          // (2*be, Wr) table, 4KB

    // bw table -> LDS (once): 128 threads x 2 float4 = 4KB
    #pragma unroll
    for (int i = 0; i < 2; ++i)
        ((float4*)bwl)[tid * 2 + i] = ((const float4*)bwg)[tid * 2 + i];

    // Wave w stages kt = 4w..4w+3 (1KB each) of each nt-tile.
    const int kt0 = wave * 4;
    const short* gB = Bh + kt0 * 512 + lane * 8;

    #define STAGE(buf, ntv) {                                                  \
        const short* _g = gB + (long)(ntv) * 4096;                             \
        _Pragma("unroll")                                                      \
        for (int kk = 0; kk < 4; ++kk)                                         \
            __builtin_amdgcn_global_load_lds((GV*)(_g + kk * 512),             \
                (LV*)&Bl[buf][(kt0 + kk) * 512], 16, 0, 0);                    \
    }

    #define VM0 asm volatile("s_waitcnt vmcnt(0)" ::: "memory");

    // ---- A-phase: coalesced row loads -> bf16 -> swizzled transpose in
    //      this wave's private scratch Bl[wave] -> fragment regs.
    bf16x8 a[MT][KT];
    char* Asl = (char*)&Bl[wave][0];     // 8KB scratch (16 rows x 512B)
    #pragma unroll
    for (int m = 0; m < MT; ++m) {
        #pragma unroll
        for (int half = 0; half < 2; ++half) {
            const float* rb = x + (row0 + m * 16 + half * 8) * D;
            float4 st[8];
            #pragma unroll
            for (int i = 0; i < 8; ++i)
                st[i] = ((const float4*)(rb + i * D))[lane];   // coalesced 1KB/inst
            #pragma unroll
            for (int i = 0; i < 8; ++i) {
                const int row = half * 8 + i;                  // local row 0..15
                short4v t;
                t[0] = f2bf(st[i].x); t[1] = f2bf(st[i].y);
                t[2] = f2bf(st[i].z); t[3] = f2bf(st[i].w);
                const int boff = row * 512 + ((lane * 8) ^ ((row & 7) << 4));
                *(short4v*)(Asl + boff) = t;
            }
        }
        #pragma unroll
        for (int kt = 0; kt < KT; ++kt) {
            const int boff = c * 512 + ((kt * 64 + g * 16) ^ ((c & 7) << 4));
            a[m][kt] = *(const bf16x8*)(Asl + boff);
        }
    }

    float lps[MT][4];
    #pragma unroll
    for (int m = 0; m < MT; ++m)
        #pragma unroll
        for (int r = 0; r < 4; ++r) lps[m][r] = 0.0f;

    f32x4 accA[MT], accB[MT];

    #define MFMA_(buf, accv) {                                                 \
        _Pragma("unroll")                                                      \
        for (int m = 0; m < MT; ++m)                                           \
            _Pragma("unroll")                                                  \
            for (int r = 0; r < 4; ++r) accv[m][r] = 0.0f;                     \
        _Pragma("unroll")                                                      \
        for (int kt = 0; kt < KT; ++kt) {                                      \
            bf16x8 b = *(const bf16x8*)&Bl[buf][kt * 512 + lane * 8];          \
            _Pragma("unroll")                                                  \
            for (int m = 0; m < MT; ++m)                                       \
                accv[m] = __builtin_amdgcn_mfma_f32_16x16x32_bf16(             \
                             a[m][kt], b, accv[m], 0, 0, 0);                   \
        }                                                                      \
    }

    #define TANH_(accv, ntv) {                                                 \
        float2 bwv = bwl[(ntv) * 16 + c];                                      \
        _Pragma("unroll")                                                      \
        for (int m = 0; m < MT; ++m)                                           \
            _Pragma("unroll")                                                  \
            for (int r = 0; r < 4; ++r) {                                      \
                float z = __builtin_fmaf(accv[m][r], 2.0f, bwv.x);             \
                float e = __expf(z);                                           \
                float rr = rcp_fast(e + 1.0f);                                 \
                lps[m][r] = __builtin_fmaf(bwv.y, rr, lps[m][r]);              \
            }                                                                  \
    }

    __syncthreads();      // both waves done with A-scratch reads; bwl visible

    // ---- Main loop: shared B dbuf; stage-other-buffer-only; VM0+barrier/nt
    STAGE(0, 0)
    VM0; __syncthreads();              // tile 0 in Bl[0]
    STAGE(1, 1)
    MFMA_(0, accA)                     // nt 0
    VM0; __syncthreads();              // tile 1 ready; buf0 reads done

    for (int it = 0; it < 15; ++it) {
        STAGE(0, 2 * it + 2)
        MFMA_(1, accB)                 // nt = 2it+1
        TANH_(accA, 2 * it)
        VM0; __syncthreads();
        STAGE(1, 2 * it + 3)
        MFMA_(0, accA)                 // nt = 2it+2
        TANH_(accB, 2 * it + 1)
        VM0; __syncthreads();
    }
    MFMA_(1, accB)                     // nt 31
    TANH_(accA, 30)
    TANH_(accB, 31)

    // ---- Reduce partials over 16 cols; softmax(sigmoid); weighted output
    const float brv = br[0];
    const float S = Ssum[0];
    #pragma unroll
    for (int m = 0; m < MT; ++m) {
        float l0 = lps[m][0], l1 = lps[m][1], l2 = lps[m][2], l3 = lps[m][3];
        #pragma unroll
        for (int off = 1; off < 16; off <<= 1) {
            l0 += __shfl_xor(l0, off, 64);
            l1 += __shfl_xor(l1, off, 64);
            l2 += __shfl_xor(l2, off, 64);
            l3 += __shfl_xor(l3, off, 64);
        }
        float g0 = S - 2.0f * l0 + brv;
        float g1 = S - 2.0f * l1 + brv;
        float g2 = S - 2.0f * l2 + brv;
        float g3 = S - 2.0f * l3 + brv;
        float s0 = rcp_fast(1.0f + __expf(-g0));
        float s1 = rcp_fast(1.0f + __expf(-g1));
        float s2 = rcp_fast(1.0f + __expf(-g2));
        float s3 = rcp_fast(1.0f + __expf(-g3));
        float e0 = __expf(s0), e1 = __expf(s1), e2 = __expf(s2), e3 = __expf(s3);
        float inv = rcp_fast(e0 + e1 + e2 + e3);
        float w0 = e0 * inv, w1 = e1 * inv, w2 = e2 * inv, w3 = e3 * inv;

        // window = rows [wrow, wrow+3]; lane-group g owns window g of this Mtile
        // lane stores cols [c*4 + q*64 ..+3]: 16 lanes -> 256B contiguous runs
        const long wrow = row0 + m * 16 + g * 4;
        const long W = wrow >> 2;
        const float* xw = x + wrow * D + c * 4;
        float* op = out + W * D + c * 4;
        #pragma unroll
        for (int q = 0; q < 4; ++q) {
            float4 r0 = *(const float4*)(xw + 0 * D + q * 64);
            float4 r1 = *(const float4*)(xw + 1 * D + q * 64);
            float4 r2 = *(const float4*)(xw + 2 * D + q * 64);
            float4 r3 = *(const float4*)(xw + 3 * D + q * 64);
            float4 oo;
            oo.x = w0 * r0.x + w1 * r1.x + w2 * r2.x + w3 * r3.x;
            oo.y = w0 * r0.y + w1 * r1.y + w2 * r2.y + w3 * r3.y;
            oo.z = w0 * r0.z + w1 * r1.z + w2 * r2.z + w3 * r3.z;
            oo.w = w0 * r0.w + w1 * r1.w + w2 * r2.w + w3 * r3.w;
            *(float4*)(op + q * 64) = oo;
        }
    }
}

extern "C" void kernel_launch(void* const* d_in, const int* in_sizes, int n_in,
                              void* d_out, int out_size, void* d_ws, size_t ws_size,
                              hipStream_t stream) {
    const float* x  = (const float*)d_in[0];
    const float* We = (const float*)d_in[1];
    const float* be = (const float*)d_in[2];
    const float* Wr = (const float*)d_in[3];
    const float* br = (const float*)d_in[4];
    float* out = (float*)d_out;

    char* ws = (char*)d_ws;
    short*  Bh   = (short*)ws;                    // 262144 B
    float2* bwp  = (float2*)(ws + 262144);        // 4096 B
    float*  Ssum = (float*)(ws + 262144 + 4096);  // 4 B

    prepack_B<<<NH * D / 256, 256, 0, stream>>>(We, be, Wr, Bh, bwp, Ssum);

    const int blocks = ROWS_TOTAL / ROWS_PER_BLOCK;   // 2048
    softpool_main<<<blocks, 128, 0, stream>>>(x, Bh, bwp, br, Ssum, out);
}

// Round 18
// 140.893 us; speedup vs baseline: 1.9811x; 1.1122x over previous
//
#include <hip/hip_runtime.h>
#include <hip/hip_bf16.h>

typedef __attribute__((ext_vector_type(8))) short bf16x8;
typedef __attribute__((ext_vector_type(4))) short short4v;
typedef __attribute__((ext_vector_type(4))) float f32x4;

#define D        256
#define NH       512
#define NT       32               // n-tiles (16 cols each)
#define KT       8                // k-steps (32 each)
#define MT       4                // M-tiles per wave -> 64 rows/wave
#define ROWS_PER_BLOCK 64         // 1 wave per block
#define ROWS_TOTAL (32*8192)      // 262144

typedef __attribute__((address_space(1))) const void GV;
typedef __attribute__((address_space(3))) void LV;

__device__ __forceinline__ short f2bf(float f) {
    union { float f; unsigned u; } v; v.f = f;
    unsigned r = v.u + 0x7FFFu + ((v.u >> 16) & 1u);
    return (short)(r >> 16);
}
__device__ __forceinline__ float rcp_fast(float x) {
    return __builtin_amdgcn_rcpf(x);
}

// Pack We (fp32 [256][512]) into bf16 MFMA B-fragments:
// frag[(nt*8+kt)*64 + lane][j] = We[kt*32 + (lane>>4)*8 + j][nt*16 + (lane&15)]
// Also: bw[n] = (2*be[n], Wr[n]); Ssum = sum(Wr).
__global__ void prepack_B(const float* __restrict__ We, const float* __restrict__ be,
                          const float* __restrict__ Wr,
                          short* __restrict__ Bh, float2* __restrict__ bw,
                          float* __restrict__ Ssum) {
    int i = blockIdx.x * 256 + threadIdx.x;      // 131072 elements
    int k = i >> 9;
    int n = i & 511;
    int nt = n >> 4, c = n & 15;
    int kt = k >> 5, g = (k >> 3) & 3, j = k & 7;
    int idx = (((nt * 8 + kt) * 64) + (g * 16 + c)) * 8 + j;
    Bh[idx] = f2bf(We[i]);
    if (i < 512) bw[i] = make_float2(2.0f * be[i], Wr[i]);
    if (i == 0) {
        float s = 0.0f;
        for (int t = 0; t < 512; ++t) s += Wr[t];
        Ssum[0] = s;
    }
}

// 1-wave blocks; coalesced A-path (row loads -> swizzled LDS transpose ->
// fragment reads); full-tile B dbuf with full VM0 drains; bw in LDS.
__global__ __launch_bounds__(64, 2) void softpool_main(
    const float* __restrict__ x, const short* __restrict__ Bh,
    const float2* __restrict__ bwg, const float* __restrict__ br,
    const float* __restrict__ Ssum, float* __restrict__ out)
{
    const int lane = threadIdx.x;        // 0..63
    const int c = lane & 15;             // A row-in-tile / C col / B col
    const int g = lane >> 4;             // k-group
    const long row0 = (long)blockIdx.x * ROWS_PER_BLOCK;

    __shared__ short Bl[2][4096];        // 2 x 8KB; Bl[0] doubles as A-scratch
    __shared__ float2 bwl[512];          // (2*be, Wr) table, 4KB

    const short* gB = Bh + lane * 8;

    #define STAGE(buf, ntv) {                                                  \
        const short* _g = gB + (long)(ntv) * 4096;                             \
        _Pragma("unroll")                                                      \
        for (int kk = 0; kk < 8; ++kk)                                         \
            __builtin_amdgcn_global_load_lds((GV*)(_g + kk * 512),             \
                (LV*)&Bl[buf][kk * 512], 16, 0, 0);                            \
    }

    #define VM0 asm volatile("s_waitcnt vmcnt(0)" ::: "memory");

    STAGE(1, 0)   // nt=0 into Bl[1]; lands during the A-phase

    // bw table -> LDS (once): 64 lanes x 4 float4 = 4KB
    #pragma unroll
    for (int i = 0; i < 4; ++i) {
        float4 v = ((const float4*)bwg)[lane * 4 + i];
        ((float4*)bwl)[lane * 4 + i] = v;
    }

    // ---- A-phase: per Mtile, coalesced row loads -> bf16 -> swizzled LDS
    //      transpose (Bl[0] as scratch) -> fragment reads into regs.
    bf16x8 a[MT][KT];
    char* Asl = (char*)&Bl[0][0];        // 8KB scratch (16 rows x 512B)
    #pragma unroll
    for (int m = 0; m < MT; ++m) {
        #pragma unroll
        for (int half = 0; half < 2; ++half) {
            const float* rb = x + (row0 + m * 16 + half * 8) * D;
            float4 st[8];
            #pragma unroll
            for (int i = 0; i < 8; ++i)
                st[i] = ((const float4*)(rb + i * D))[lane];   // coalesced 1KB/inst
            #pragma unroll
            for (int i = 0; i < 8; ++i) {
                const int row = half * 8 + i;                  // local row 0..15
                short4v t;
                t[0] = f2bf(st[i].x); t[1] = f2bf(st[i].y);
                t[2] = f2bf(st[i].z); t[3] = f2bf(st[i].w);
                const int boff = row * 512 + ((lane * 8) ^ ((row & 7) << 4));
                *(short4v*)(Asl + boff) = t;
            }
        }
        #pragma unroll
        for (int kt = 0; kt < KT; ++kt) {
            const int boff = c * 512 + ((kt * 64 + g * 16) ^ ((c & 7) << 4));
            a[m][kt] = *(const bf16x8*)(Asl + boff);
        }
    }

    float lps[MT][4];
    #pragma unroll
    for (int m = 0; m < MT; ++m)
        #pragma unroll
        for (int r = 0; r < 4; ++r) lps[m][r] = 0.0f;

    f32x4 accA[MT], accB[MT];

    #define MFMA_(buf, accv) {                                                 \
        _Pragma("unroll")                                                      \
        for (int m = 0; m < MT; ++m)                                           \
            _Pragma("unroll")                                                  \
            for (int r = 0; r < 4; ++r) accv[m][r] = 0.0f;                     \
        _Pragma("unroll")                                                      \
        for (int kt = 0; kt < KT; ++kt) {                                      \
            bf16x8 b = *(const bf16x8*)&Bl[buf][kt * 512 + lane * 8];          \
            _Pragma("unroll")                                                  \
            for (int m = 0; m < MT; ++m)                                       \
                accv[m] = __builtin_amdgcn_mfma_f32_16x16x32_bf16(             \
                             a[m][kt], b, accv[m], 0, 0, 0);                   \
        }                                                                      \
    }

    #define TANH_(accv, ntv) {                                                 \
        float2 bwv = bwl[(ntv) * 16 + c];                                      \
        _Pragma("unroll")                                                      \
        for (int m = 0; m < MT; ++m)                                           \
            _Pragma("unroll")                                                  \
            for (int r = 0; r < 4; ++r) {                                      \
                float z = __builtin_fmaf(accv[m][r], 2.0f, bwv.x);             \
                float e = __expf(z);                                           \
                float rr = rcp_fast(e + 1.0f);                                 \
                lps[m][r] = __builtin_fmaf(bwv.y, rr, lps[m][r]);              \
            }                                                                  \
    }

    // even nt -> Bl[1], odd nt -> Bl[0] (A-scratch is free after the A-phase)
    VM0               // nt=0 staged
    STAGE(0, 1)
    MFMA_(1, accA)    // nt 0
    VM0               // nt=1 landed

    for (int it = 0; it < 15; ++it) {
        STAGE(1, 2 * it + 2)
        MFMA_(0, accB)               // nt = 2it+1
        TANH_(accA, 2 * it)
        VM0
        STAGE(0, 2 * it + 3)
        MFMA_(1, accA)               // nt = 2it+2
        TANH_(accB, 2 * it + 1)
        VM0
    }
    MFMA_(0, accB)                   // nt 31
    TANH_(accA, 30)
    TANH_(accB, 31)

    // ---- Reduce partials over 16 cols; softmax(sigmoid); weighted output
    const float brv = br[0];
    const float S = Ssum[0];
    #pragma unroll
    for (int m = 0; m < MT; ++m) {
        float l0 = lps[m][0], l1 = lps[m][1], l2 = lps[m][2], l3 = lps[m][3];
        #pragma unroll
        for (int off = 1; off < 16; off <<= 1) {
            l0 += __shfl_xor(l0, off, 64);
            l1 += __shfl_xor(l1, off, 64);
            l2 += __shfl_xor(l2, off, 64);
            l3 += __shfl_xor(l3, off, 64);
        }
        float g0 = S - 2.0f * l0 + brv;
        float g1 = S - 2.0f * l1 + brv;
        float g2 = S - 2.0f * l2 + brv;
        float g3 = S - 2.0f * l3 + brv;
        float s0 = rcp_fast(1.0f + __expf(-g0));
        float s1 = rcp_fast(1.0f + __expf(-g1));
        float s2 = rcp_fast(1.0f + __expf(-g2));
        float s3 = rcp_fast(1.0f + __expf(-g3));
        float e0 = __expf(s0), e1 = __expf(s1), e2 = __expf(s2), e3 = __expf(s3);
        float inv = rcp_fast(e0 + e1 + e2 + e3);
        float w0 = e0 * inv, w1 = e1 * inv, w2 = e2 * inv, w3 = e3 * inv;

        // window = rows [wrow, wrow+3]; lane-group g owns window g of this Mtile
        // lane stores cols [c*4 + q*64 ..+3]: 16 lanes -> 256B contiguous runs
        const long wrow = row0 + m * 16 + g * 4;
        const long W = wrow >> 2;
        const float* xw = x + wrow * D + c * 4;
        float* op = out + W * D + c * 4;
        #pragma unroll
        for (int q = 0; q < 4; ++q) {
            float4 r0 = *(const float4*)(xw + 0 * D + q * 64);
            float4 r1 = *(const float4*)(xw + 1 * D + q * 64);
            float4 r2 = *(const float4*)(xw + 2 * D + q * 64);
            float4 r3 = *(const float4*)(xw + 3 * D + q * 64);
            float4 oo;
            oo.x = w0 * r0.x + w1 * r1.x + w2 * r2.x + w3 * r3.x;
            oo.y = w0 * r0.y + w1 * r1.y + w2 * r2.y + w3 * r3.y;
            oo.z = w0 * r0.z + w1 * r1.z + w2 * r2.z + w3 * r3.z;
            oo.w = w0 * r0.w + w1 * r1.w + w2 * r2.w + w3 * r3.w;
            *(float4*)(op + q * 64) = oo;
        }
    }
}

extern "C" void kernel_launch(void* const* d_in, const int* in_sizes, int n_in,
                              void* d_out, int out_size, void* d_ws, size_t ws_size,
                              hipStream_t stream) {
    const float* x  = (const float*)d_in[0];
    const float* We = (const float*)d_in[1];
    const float* be = (const float*)d_in[2];
    const float* Wr = (const float*)d_in[3];
    const float* br = (const float*)d_in[4];
    float* out = (float*)d_out;

    char* ws = (char*)d_ws;
    short*  Bh   = (short*)ws;                    // 262144 B
    float2* bwp  = (float2*)(ws + 262144);        // 4096 B
    float*  Ssum = (float*)(ws + 262144 + 4096);  // 4 B

    prepack_B<<<NH * D / 256, 256, 0, stream>>>(We, be, Wr, Bh, bwp, Ssum);

    const int blocks = ROWS_TOTAL / ROWS_PER_BLOCK;   // 4096
    softpool_main<<<blocks, 64, 0, stream>>>(x, Bh, bwp, br, Ssum, out);
}

// Round 20
// 136.904 us; speedup vs baseline: 2.0388x; 1.0291x over previous
//
#include <hip/hip_runtime.h>
#include <hip/hip_bf16.h>

typedef __attribute__((ext_vector_type(8))) short bf16x8;
typedef __attribute__((ext_vector_type(4))) short short4v;
typedef __attribute__((ext_vector_type(4))) float f32x4;

#define D        256
#define NH       512
#define NT       32               // n-tiles (16 cols each)
#define KT       8                // k-steps (32 each)
#define MT       4                // M-tiles per wave -> 64 rows/wave
#define ROWS_PER_BLOCK 64         // 1 wave per block
#define ROWS_TOTAL (32*8192)      // 262144

typedef __attribute__((address_space(1))) const void GV;
typedef __attribute__((address_space(3))) void LV;

__device__ __forceinline__ short f2bf(float f) {
    union { float f; unsigned u; } v; v.f = f;
    unsigned r = v.u + 0x7FFFu + ((v.u >> 16) & 1u);
    return (short)(r >> 16);
}
__device__ __forceinline__ float rcp_fast(float x) {
    return __builtin_amdgcn_rcpf(x);
}

// Pack We (fp32 [256][512]) into bf16 MFMA B-fragments:
// frag[(nt*8+kt)*64 + lane][j] = We[kt*32 + (lane>>4)*8 + j][nt*16 + (lane&15)]
// Also: bw[n] = (2*be[n], Wr[n]).  (No Ssum: logit = -2*sum(Wr*(rcp-0.5)) + br)
__global__ void prepack_B(const float* __restrict__ We, const float* __restrict__ be,
                          const float* __restrict__ Wr,
                          short* __restrict__ Bh, float2* __restrict__ bw) {
    int i = blockIdx.x * 256 + threadIdx.x;      // 131072 elements
    int k = i >> 9;
    int n = i & 511;
    int nt = n >> 4, c = n & 15;
    int kt = k >> 5, g = (k >> 3) & 3, j = k & 7;
    int idx = (((nt * 8 + kt) * 64) + (g * 16 + c)) * 8 + j;
    Bh[idx] = f2bf(We[i]);
    if (i < 512) bw[i] = make_float2(2.0f * be[i], Wr[i]);
}

// 1-wave blocks; coalesced A-path (row loads -> swizzled LDS transpose ->
// fragment reads); full-tile B dbuf with full VM0 drains (the ONLY re-stage
// discipline that is race-free on this toolchain); bw table in LDS.
__global__ __launch_bounds__(64, 2) void softpool_main(
    const float* __restrict__ x, const short* __restrict__ Bh,
    const float2* __restrict__ bwg, const float* __restrict__ br,
    float* __restrict__ out)
{
    const int lane = threadIdx.x;        // 0..63
    const int c = lane & 15;             // A row-in-tile / C col / B col
    const int g = lane >> 4;             // k-group
    const long row0 = (long)blockIdx.x * ROWS_PER_BLOCK;

    __shared__ short Bl[2][4096];        // 2 x 8KB; Bl[0] doubles as A-scratch
    __shared__ float2 bwl[512];          // (2*be, Wr) table, 4KB

    const short* gB = Bh + lane * 8;

    #define STAGE(buf, ntv) {                                                  \
        const short* _g = gB + (long)(ntv) * 4096;                             \
        _Pragma("unroll")                                                      \
        for (int kk = 0; kk < 8; ++kk)                                         \
            __builtin_amdgcn_global_load_lds((GV*)(_g + kk * 512),             \
                (LV*)&Bl[buf][kk * 512], 16, 0, 0);                            \
    }

    #define VM0 asm volatile("s_waitcnt vmcnt(0)" ::: "memory");

    STAGE(1, 0)   // nt=0 into Bl[1]; lands during the A-phase

    // bw table -> LDS (once): 64 lanes x 4 float4 = 4KB
    #pragma unroll
    for (int i = 0; i < 4; ++i) {
        float4 v = ((const float4*)bwg)[lane * 4 + i];
        ((float4*)bwl)[lane * 4 + i] = v;
    }

    // ---- A-phase: per Mtile, coalesced row loads -> bf16 -> swizzled LDS
    //      transpose (Bl[0] as scratch) -> fragment reads into regs.
    bf16x8 a[MT][KT];
    char* Asl = (char*)&Bl[0][0];        // 8KB scratch (16 rows x 512B)
    #pragma unroll
    for (int m = 0; m < MT; ++m) {
        #pragma unroll
        for (int half = 0; half < 2; ++half) {
            const float* rb = x + (row0 + m * 16 + half * 8) * D;
            float4 st[8];
            #pragma unroll
            for (int i = 0; i < 8; ++i)
                st[i] = ((const float4*)(rb + i * D))[lane];   // coalesced 1KB/inst
            #pragma unroll
            for (int i = 0; i < 8; ++i) {
                const int row = half * 8 + i;                  // local row 0..15
                short4v t;
                t[0] = f2bf(st[i].x); t[1] = f2bf(st[i].y);
                t[2] = f2bf(st[i].z); t[3] = f2bf(st[i].w);
                const int boff = row * 512 + ((lane * 8) ^ ((row & 7) << 4));
                *(short4v*)(Asl + boff) = t;
            }
        }
        #pragma unroll
        for (int kt = 0; kt < KT; ++kt) {
            const int boff = c * 512 + ((kt * 64 + g * 16) ^ ((c & 7) << 4));
            a[m][kt] = *(const bf16x8*)(Asl + boff);
        }
    }

    float lps[MT][4];
    #pragma unroll
    for (int m = 0; m < MT; ++m)
        #pragma unroll
        for (int r = 0; r < 4; ++r) lps[m][r] = 0.0f;

    f32x4 accA[MT], accB[MT];

    #define MFMA_(buf, accv) {                                                 \
        _Pragma("unroll")                                                      \
        for (int m = 0; m < MT; ++m)                                           \
            _Pragma("unroll")                                                  \
            for (int r = 0; r < 4; ++r) accv[m][r] = 0.0f;                     \
        _Pragma("unroll")                                                      \
        for (int kt = 0; kt < KT; ++kt) {                                      \
            bf16x8 b = *(const bf16x8*)&Bl[buf][kt * 512 + lane * 8];          \
            _Pragma("unroll")                                                  \
            for (int m = 0; m < MT; ++m)                                       \
                accv[m] = __builtin_amdgcn_mfma_f32_16x16x32_bf16(             \
                             a[m][kt], b, accv[m], 0, 0, 0);                   \
        }                                                                      \
    }

    // lps += Wr * (rcp(exp(2y)+1) - 0.5)  =>  logit = -2*lps_total + br
    #define TANH_(accv, ntv) {                                                 \
        float2 bwv = bwl[(ntv) * 16 + c];                                      \
        _Pragma("unroll")                                                      \
        for (int m = 0; m < MT; ++m)                                           \
            _Pragma("unroll")                                                  \
            for (int r = 0; r < 4; ++r) {                                      \
                float z = __builtin_fmaf(accv[m][r], 2.0f, bwv.x);             \
                float e = __expf(z);                                           \
                float rr = rcp_fast(e + 1.0f) - 0.5f;                          \
                lps[m][r] = __builtin_fmaf(bwv.y, rr, lps[m][r]);              \
            }                                                                  \
    }

    // even nt -> Bl[1], odd nt -> Bl[0] (A-scratch is free after the A-phase)
    VM0               // nt=0 staged
    STAGE(0, 1)
    MFMA_(1, accA)    // nt 0
    VM0               // nt=1 landed

    for (int it = 0; it < 15; ++it) {
        STAGE(1, 2 * it + 2)
        MFMA_(0, accB)               // nt = 2it+1
        TANH_(accA, 2 * it)
        VM0
        STAGE(0, 2 * it + 3)
        MFMA_(1, accA)               // nt = 2it+2
        TANH_(accB, 2 * it + 1)
        VM0
    }
    MFMA_(0, accB)                   // nt 31
    TANH_(accA, 30)
    TANH_(accB, 31)

    // ---- Reduce partials over 16 cols; softmax(sigmoid); weighted output
    const float brv = br[0];
    #pragma unroll
    for (int m = 0; m < MT; ++m) {
        float l0 = lps[m][0], l1 = lps[m][1], l2 = lps[m][2], l3 = lps[m][3];
        #pragma unroll
        for (int off = 1; off < 16; off <<= 1) {
            l0 += __shfl_xor(l0, off, 64);
            l1 += __shfl_xor(l1, off, 64);
            l2 += __shfl_xor(l2, off, 64);
            l3 += __shfl_xor(l3, off, 64);
        }
        float g0 = __builtin_fmaf(-2.0f, l0, brv);
        float g1 = __builtin_fmaf(-2.0f, l1, brv);
        float g2 = __builtin_fmaf(-2.0f, l2, brv);
        float g3 = __builtin_fmaf(-2.0f, l3, brv);
        float s0 = rcp_fast(1.0f + __expf(-g0));
        float s1 = rcp_fast(1.0f + __expf(-g1));
        float s2 = rcp_fast(1.0f + __expf(-g2));
        float s3 = rcp_fast(1.0f + __expf(-g3));
        float e0 = __expf(s0), e1 = __expf(s1), e2 = __expf(s2), e3 = __expf(s3);
        float inv = rcp_fast(e0 + e1 + e2 + e3);
        float w0 = e0 * inv, w1 = e1 * inv, w2 = e2 * inv, w3 = e3 * inv;

        // window = rows [wrow, wrow+3]; lane-group g owns window g of this Mtile
        // lane stores cols [c*4 + q*64 ..+3]: 16 lanes -> 256B contiguous runs
        const long wrow = row0 + m * 16 + g * 4;
        const long W = wrow >> 2;
        const float* xw = x + wrow * D + c * 4;
        float* op = out + W * D + c * 4;
        #pragma unroll
        for (int q = 0; q < 4; ++q) {
            float4 r0 = *(const float4*)(xw + 0 * D + q * 64);
            float4 r1 = *(const float4*)(xw + 1 * D + q * 64);
            float4 r2 = *(const float4*)(xw + 2 * D + q * 64);
            float4 r3 = *(const float4*)(xw + 3 * D + q * 64);
            float4 oo;
            oo.x = w0 * r0.x + w1 * r1.x + w2 * r2.x + w3 * r3.x;
            oo.y = w0 * r0.y + w1 * r1.y + w2 * r2.y + w3 * r3.y;
            oo.z = w0 * r0.z + w1 * r1.z + w2 * r2.z + w3 * r3.z;
            oo.w = w0 * r0.w + w1 * r1.w + w2 * r2.w + w3 * r3.w;
            *(float4*)(op + q * 64) = oo;
        }
    }
}

extern "C" void kernel_launch(void* const* d_in, const int* in_sizes, int n_in,
                              void* d_out, int out_size, void* d_ws, size_t ws_size,
                              hipStream_t stream) {
    const float* x  = (const float*)d_in[0];
    const float* We = (const float*)d_in[1];
    const float* be = (const float*)d_in[2];
    const float* Wr = (const float*)d_in[3];
    const float* br = (const float*)d_in[4];
    float* out = (float*)d_out;

    char* ws = (char*)d_ws;
    short*  Bh  = (short*)ws;                    // 262144 B
    float2* bwp = (float2*)(ws + 262144);        // 4096 B

    prepack_B<<<NH * D / 256, 256, 0, stream>>>(We, be, Wr, Bh, bwp);

    const int blocks = ROWS_TOTAL / ROWS_PER_BLOCK;   // 4096
    softpool_main<<<blocks, 64, 0, stream>>>(x, Bh, bwp, br, out);
}